// Round 9
// baseline (306.730 us; speedup 1.0000x reference)
//
#include <hip/hip_runtime.h>
#include <math.h>

constexpr int Bc = 32;     // batch
constexpr int Tc = 1000;   // time
constexpr int Vc = 1024;   // vocab
constexpr int Lc = 128;    // label length
constexpr int Sc = 2 * Lc + 1;  // 257 lattice states
constexpr int SP = 320;         // padded stride (positions 0..319)
constexpr float NEGF = -1e30f;
constexpr float L2E = 1.4426950408889634f;   // log2(e)
constexpr float LN2 = 0.6931471805599453f;   // ln(2)
constexpr int ENEG = -(1 << 24);             // sentinel exponent: "no mass"

#if __has_builtin(__builtin_amdgcn_exp2f)
#define EXP2F(x) __builtin_amdgcn_exp2f(x)
#else
#define EXP2F(x) exp2f(x)
#endif
#if __has_builtin(__builtin_amdgcn_logf)
#define LOG2F(x) __builtin_amdgcn_logf(x)
#else
#define LOG2F(x) log2f(x)
#endif
#if __has_builtin(__builtin_amdgcn_ldexpf)
#define LDEXPF(x, e) __builtin_amdgcn_ldexpf(x, e)
#else
#define LDEXPF(x, e) ldexpf(x, e)
#endif
#if __has_builtin(__builtin_amdgcn_frexp_expf)
#define FREXPE(x) __builtin_amdgcn_frexp_expf(x)
#else
__device__ inline int FREXPE(float x) { int e; (void)frexpf(x, &e); return e; }
#endif

// Layout: lane l holds states s = 4l+j (slots j=0..3) stored CONTIGUOUSLY at
// position 4l+j (float4-able!), plus state 256 in slot 4 of lane 63 at
// position 256+lane. Slots 0,2,4 = blanks; 1,3 = labels. One cross-lane
// value per step: state 4l-1 = lane l-1 slot 3. Values = LINEAR probs.

// ---------------------------------------------------------------------------
// Kernel A: log-softmax + gather, one WAVE per (b,t) row; linear probs.
// Blank prob computed once per wave; one dwordx4 + one dword store per lane.
// ---------------------------------------------------------------------------
__global__ __launch_bounds__(256) void ctc_lse_gather(
    const float* __restrict__ hs, const int* __restrict__ ys,
    float* __restrict__ lpe) {
  const int wv = threadIdx.x >> 6;
  const int lane = threadIdx.x & 63;
  const int bt = blockIdx.x * 4 + wv;   // row index b*Tc + t
  const int b = bt / Tc;
  const float* row = hs + (size_t)bt * Vc;

  __shared__ float xs_all[4][Vc];
  float* xs = xs_all[wv];

  float4 v[4];
#pragma unroll
  for (int q = 0; q < 4; ++q) v[q] = reinterpret_cast<const float4*>(row)[lane + 64 * q];
#pragma unroll
  for (int q = 0; q < 4; ++q) { v[q].x *= L2E; v[q].y *= L2E; v[q].z *= L2E; v[q].w *= L2E; }

  float m = -3.4e38f;
#pragma unroll
  for (int q = 0; q < 4; ++q)
    m = fmaxf(m, fmaxf(fmaxf(v[q].x, v[q].y), fmaxf(v[q].z, v[q].w)));
#pragma unroll
  for (int off = 32; off; off >>= 1) m = fmaxf(m, __shfl_xor(m, off, 64));

  float sum = 0.f;
#pragma unroll
  for (int q = 0; q < 4; ++q)
    sum += EXP2F(v[q].x - m) + EXP2F(v[q].y - m) + EXP2F(v[q].z - m) + EXP2F(v[q].w - m);
#pragma unroll
  for (int off = 32; off; off >>= 1) sum += __shfl_xor(sum, off, 64);
  const float lse2 = m + LOG2F(sum);

#pragma unroll
  for (int q = 0; q < 4; ++q) reinterpret_cast<float4*>(xs)[lane + 64 * q] = v[q];
  __syncthreads();

  const float pblank = EXP2F(xs[0] - lse2);  // wave-uniform
  const int2 yy = *reinterpret_cast<const int2*>(ys + b * Lc + 2 * lane);
  float4 o;
  o.x = pblank;                    // s = 4l   (blank)
  o.y = EXP2F(xs[yy.x] - lse2);    // s = 4l+1 (label ys[2l])
  o.z = pblank;                    // s = 4l+2 (blank)
  o.w = EXP2F(xs[yy.y] - lse2);    // s = 4l+3 (label ys[2l+1])
  float* out = lpe + (size_t)bt * SP;
  *reinterpret_cast<float4*>(out + 4 * lane) = o;
  out[256 + lane] = (lane == 63) ? pblank : 0.f;   // state 256 / padding
}

// ---------------------------------------------------------------------------
// Kernel B: CTC alpha, linear domain + per-lane integer exponent.
// Scale reconcile hoisted to every 2 steps: shuffle E by 1 AND 2 lanes
// (parallel), left's working scale Ets=max(Ep,Epp) computed locally, one
// sf = 2^(Ets-Et) reused by both steps. Inner steps: zero ldexp/frexp.
// ---------------------------------------------------------------------------
__global__ __launch_bounds__(64) void ctc_alpha(
    const float* __restrict__ lpe, const int* __restrict__ ys,
    const int* __restrict__ hlen, const int* __restrict__ ylen,
    float* __restrict__ lossb) {
  const int b = blockIdx.x;
  const int lane = threadIdx.x;
  const float* pb = lpe + (size_t)b * Tc * SP;
  const int* yb = ys + b * Lc;

  const float sk1 = (lane >= 1 && yb[2 * lane - 1] != yb[2 * lane]) ? 1.f : 0.f;
  const float sk3 = (yb[2 * lane] != yb[2 * lane + 1]) ? 1.f : 0.f;

  // t=0: states 0,1 live on lane 0 (positions 0,1)
  float m0 = (lane == 0) ? pb[0] : 0.f;
  float m1 = (lane == 0) ? pb[1] : 0.f;
  float m2 = 0.f, m3 = 0.f, m4 = 0.f;
  int E = (lane == 0) ? 0 : ENEG;

  const int Te = min(hlen[b], Tc);

  // ---- 2-step pair with hoisted scale reconcile ----
  auto pair = [&](const float* pA, const float* pB) {
    int Ep = __shfl_up(E, 1, 64);
    int Epp = __shfl_up(E, 2, 64);
    if (lane == 0) { Ep = ENEG; Epp = ENEG; }
    if (lane == 1) { Epp = ENEG; }
    const int Et = max(E, Ep);
    const int Ets = max(Ep, Epp);           // left lane's working scale
    const float sf = (Ep == ENEG) ? 0.f : LDEXPF(1.f, min(Ets - Et, 126));
    const int dm = E - Et;                  // <= 0
    m0 = LDEXPF(m0, dm); m1 = LDEXPF(m1, dm); m2 = LDEXPF(m2, dm);
    m3 = LDEXPF(m3, dm); m4 = LDEXPF(m4, dm);
    E = Et;
    // step A
    float msh = __shfl_up(m3, 1, 64);
    if (lane == 0) msh = 0.f;
    const float am = msh * sf;
    const float n0 = (m0 + am) * pA[0];
    const float n1 = fmaf(sk1, am, m1 + m0) * pA[1];
    const float n2 = (n1 == n1) ? (m2 + m1) * pA[2] : 0.f;  // (n1 always finite; keep simple)
    const float n2b = (m2 + m1) * pA[2];
    const float n3 = fmaf(sk3, m1, m3 + m2) * pA[3];
    const float n4 = (m4 + m3) * pA[4];
    (void)n2;
    // step B
    float msh2 = __shfl_up(n3, 1, 64);
    if (lane == 0) msh2 = 0.f;
    const float am2 = msh2 * sf;
    m0 = (n0 + am2) * pB[0];
    m1 = fmaf(sk1, am2, n1 + n0) * pB[1];
    m2 = (n2b + n1) * pB[2];
    m3 = fmaf(sk3, n1, n3 + n2b) * pB[3];
    m4 = (n4 + n3) * pB[4];
    // renorm (amortized)
    const float mx = fmaxf(fmaxf(fmaxf(m0, m1), fmaxf(m2, m3)), m4);
    const int e = FREXPE(mx);
    E = (mx > 0.f) ? (E + e) : ENEG;
    m0 = LDEXPF(m0, -e); m1 = LDEXPF(m1, -e); m2 = LDEXPF(m2, -e);
    m3 = LDEXPF(m3, -e); m4 = LDEXPF(m4, -e);
  };

  // ---- single step with full per-step reconcile (tail only) ----
  auto step1 = [&](const float* p) {
    float msh = __shfl_up(m3, 1, 64);
    int Esh = __shfl_up(E, 1, 64);
    if (lane == 0) { msh = 0.f; Esh = ENEG; }
    const int Et = max(E, Esh);
    const int dm = E - Et, dsh = Esh - Et;
    const float am = LDEXPF(msh, dsh);
    const float a0 = LDEXPF(m0, dm), a1 = LDEXPF(m1, dm), a2 = LDEXPF(m2, dm);
    const float a3 = LDEXPF(m3, dm), a4 = LDEXPF(m4, dm);
    const float n0 = (a0 + am) * p[0];
    const float n1 = fmaf(sk1, am, a1 + a0) * p[1];
    const float n2 = (a2 + a1) * p[2];
    const float n3 = fmaf(sk3, a1, a3 + a2) * p[3];
    const float n4 = (a4 + a3) * p[4];
    const float mx = fmaxf(fmaxf(fmaxf(n0, n1), fmaxf(n2, n3)), n4);
    const int e = FREXPE(mx);
    E = (mx > 0.f) ? (Et + e) : ENEG;
    m0 = LDEXPF(n0, -e); m1 = LDEXPF(n1, -e); m2 = LDEXPF(n2, -e);
    m3 = LDEXPF(n3, -e); m4 = LDEXPF(n4, -e);
  };

  float bufA[8][5], bufB[8][5];
  auto load8A = [&](int trow) {
    const float* p = pb + (size_t)trow * SP;
#pragma unroll
    for (int k = 0; k < 8; ++k) {
      const float4 q = *reinterpret_cast<const float4*>(p + k * SP + 4 * lane);
      bufA[k][0] = q.x; bufA[k][1] = q.y; bufA[k][2] = q.z; bufA[k][3] = q.w;
      bufA[k][4] = p[k * SP + 256 + lane];
    }
  };
  auto load8B = [&](int trow) {
    const float* p = pb + (size_t)trow * SP;
#pragma unroll
    for (int k = 0; k < 8; ++k) {
      const float4 q = *reinterpret_cast<const float4*>(p + k * SP + 4 * lane);
      bufB[k][0] = q.x; bufB[k][1] = q.y; bufB[k][2] = q.z; bufB[k][3] = q.w;
      bufB[k][4] = p[k * SP + 256 + lane];
    }
  };

  int t = 1;
  if (t + 8 <= Te) load8A(t);
  while (t + 16 <= Te) {
    load8B(t + 8);
    pair(bufA[0], bufA[1]); pair(bufA[2], bufA[3]);
    pair(bufA[4], bufA[5]); pair(bufA[6], bufA[7]);
    t += 8;
    if (t + 16 <= Te) load8A(t + 8);
    pair(bufB[0], bufB[1]); pair(bufB[2], bufB[3]);
    pair(bufB[4], bufB[5]); pair(bufB[6], bufB[7]);
    t += 8;
  }
  if (t + 8 <= Te) {
    pair(bufA[0], bufA[1]); pair(bufA[2], bufA[3]);
    pair(bufA[4], bufA[5]); pair(bufA[6], bufA[7]);
    t += 8;
  }
  while (t + 2 <= Te) {
    float pA[5], pB[5];
    const float* p = pb + (size_t)t * SP;
    const float4 qa = *reinterpret_cast<const float4*>(p + 4 * lane);
    pA[0] = qa.x; pA[1] = qa.y; pA[2] = qa.z; pA[3] = qa.w; pA[4] = p[256 + lane];
    const float4 qb = *reinterpret_cast<const float4*>(p + SP + 4 * lane);
    pB[0] = qb.x; pB[1] = qb.y; pB[2] = qb.z; pB[3] = qb.w; pB[4] = p[SP + 256 + lane];
    pair(pA, pB);
    t += 2;
  }
  while (t < Te) {
    float lp[5];
    const float* p = pb + (size_t)t * SP;
    const float4 q = *reinterpret_cast<const float4*>(p + 4 * lane);
    lp[0] = q.x; lp[1] = q.y; lp[2] = q.z; lp[3] = q.w; lp[4] = p[256 + lane];
    step1(lp);
    ++t;
  }

  // final: loss = -ln2 * log2(alpha[2L] + alpha[2L-1]) / ylen
  __shared__ float msm[SP];
  __shared__ int esm[64];
  msm[4 * lane + 0] = m0; msm[4 * lane + 1] = m1;
  msm[4 * lane + 2] = m2; msm[4 * lane + 3] = m3;
  if (lane == 63) msm[256] = m4;
  esm[lane] = E;
  __syncthreads();
  if (lane == 0) {
    const int yl = ylen[b];
    const int s1 = 2 * yl, s0 = 2 * yl - 1;
    const int l1 = (s1 == 256) ? 63 : (s1 >> 2);
    const int l0 = s0 >> 2;
    const float vx = msm[s1]; const int ex = esm[l1];
    const float vy = msm[s0]; const int ey = esm[l0];
    const int Em = max(ex, ey);
    const float r = LDEXPF(vx, ex - Em) + LDEXPF(vy, ey - Em);
    const float ae2 = (r > 0.f) ? (LOG2F(r) + (float)Em) : NEGF;
    lossb[b] = -(ae2 * LN2) / (float)yl;
  }
}

// ---------------------------------------------------------------------------
// Kernel C: mean over batch
// ---------------------------------------------------------------------------
__global__ __launch_bounds__(64) void ctc_final(
    const float* __restrict__ lossb, float* __restrict__ out) {
  const int lane = threadIdx.x;
  float v = (lane < Bc) ? lossb[lane] : 0.f;
#pragma unroll
  for (int off = 32; off; off >>= 1) v += __shfl_xor(v, off, 64);
  if (lane == 0) out[0] = v * (1.f / (float)Bc);
}

extern "C" void kernel_launch(void* const* d_in, const int* in_sizes, int n_in,
                              void* d_out, int out_size, void* d_ws, size_t ws_size,
                              hipStream_t stream) {
  const float* hs = (const float*)d_in[0];    // (B,T,V) fp32
  const int* hlen = (const int*)d_in[1];      // (B,)
  const int* ys = (const int*)d_in[2];        // (B,L)
  const int* ylen = (const int*)d_in[3];      // (B,)
  float* out = (float*)d_out;                 // scalar

  float* lpe = (float*)d_ws;                             // B*T*SP floats (~41 MB)
  float* lossb = lpe + (size_t)Bc * Tc * SP;             // B floats

  ctc_lse_gather<<<Bc * Tc / 4, 256, 0, stream>>>(hs, ys, lpe);
  ctc_alpha<<<Bc, 64, 0, stream>>>(lpe, ys, hlen, ylen, lossb);
  ctc_final<<<1, 64, 0, stream>>>(lossb, out);
}